// Round 10
// baseline (68.028 us; speedup 1.0000x reference)
//
#include <hip/hip_runtime.h>
#include <hip/hip_bf16.h>
#include <math.h>

#define NNODES 8192
#define DIM 128
#define SMAX 128
#define HSIZE 16384   // hash table capacity (power of 2)
#define NBD 256
#define NTD 1024
#define LDA 132       // padded LDS stride: keeps 16B alignment, spreads banks

// Per-thread index-dtype detection: reads first 4 int64-interpretations of row.
__device__ __forceinline__ int detect64(const void* rowp) {
    const long long* p = (const long long*)rowp;
    int is64 = 1;
#pragma unroll
    for (int i = 0; i < 4; i++) {
        long long v = p[i];
        if (v < 0 || v >= NNODES) is64 = 0;
    }
    return is64;
}

__device__ __forceinline__ int edge_idx(const void* p, int e, int idx64) {
    if (idx64) return (int)((const long long*)p)[e];
    return ((const int*)p)[e];
}

__device__ __forceinline__ int hash_insert(unsigned int* hashK, unsigned int key1) {
    unsigned int h = (key1 * 2654435761u) & (HSIZE - 1);
    for (;;) {
        unsigned int prev = atomicCAS(&hashK[h], 0u, key1);
        if (prev == 0u || prev == key1) return (int)h;
        h = (h + 1) & (HSIZE - 1);
    }
}

// Force a (wave-uniform) pointer into SGPRs so W reads become s_loads.
__device__ __forceinline__ const float* uniform_ptr(const float* p) {
    unsigned long long u = (unsigned long long)p;
    unsigned int lo = __builtin_amdgcn_readfirstlane((unsigned int)u);
    unsigned int hi = __builtin_amdgcn_readfirstlane((unsigned int)(u >> 32));
    return (const float*)(((unsigned long long)hi << 32) | lo);
}

// --- K0: zero scratch (rocclr fillBuffer is ~39us even for small sizes) ---
__global__ __launch_bounds__(256) void k_zero(float4* z, int n4) {
    int i = blockIdx.x * blockDim.x + threadIdx.x;
    if (i < n4) z[i] = make_float4(0.f, 0.f, 0.f, 0.f);
}

// --- K1: dense precompute (U,V,xw,cself) + nodeid mark & slot assignment ---
// lane = output row: A via per-lane ds_read_b128 (1 LDS op / 4 d);
// wave owns 8 output cols: W wave-uniform -> scalar loads via uniform_ptr.
// (r8 lesson: broadcast LDS reads = LDS-pipe bound; r9 lesson: readlane
//  broadcast = 2x VALU. Correct form: per-lane A, SGPR-operand W.)
__global__ __launch_bounds__(NTD) void k_dense(
        const float* embed, const float* x, const float* W1e, const float* b1e,
        const float* Wg0, const int* nodep, const void* rowp, const void* colp,
        const float* adjd,
        float* U, float* V, float* xw, float* cself,
        int* flags, float* cnt0, int* nbr, int* slotmap, int E) {
    int bid = blockIdx.x;
    int t = threadIdx.x;
    int w = t >> 6;
    int lane = t & 63;
    int nodeid = nodep[0];
    __shared__ float smf[64 * LDA];   // 33.8 KB
    __shared__ float semb[DIM];

    int tile = bid;
    const float* src = (tile < 128) ? embed + (size_t)tile * 64 * DIM
                                    : x + (size_t)(tile - 128) * 64 * DIM;
    for (int i = t; i < 64 * DIM; i += NTD)
        smf[(i >> 7) * LDA + (i & 127)] = src[i];
    if (bid == 255 && t < DIM) semb[t] = embed[(size_t)nodeid * DIM + t];
    __syncthreads();

    const float* Wbase;
    float* outp;
    int ldw, ldo, cb;
    if (tile < 128) {
        if (w < 8) { Wbase = W1e;            cb = w * 8;       outp = U; }
        else       { Wbase = W1e + 128 * 64; cb = (w - 8) * 8; outp = V; }
        ldw = 64; ldo = 64;
    } else {
        Wbase = Wg0; cb = w * 8; ldw = DIM; outp = xw; ldo = DIM;
    }
    const float* Wu = uniform_ptr(Wbase + cb);   // SGPR base -> s_load W reads

    float acc[8] = {0, 0, 0, 0, 0, 0, 0, 0};
    for (int d0 = 0; d0 < DIM; d0 += 4) {
        float4 a4 = *(const float4*)&smf[lane * LDA + d0];
#pragma unroll
        for (int dd = 0; dd < 4; dd++) {
            float a = (&a4.x)[dd];
            const float* wr = Wu + (size_t)(d0 + dd) * ldw;
#pragma unroll
            for (int j = 0; j < 8; j++)
                acc[j] = fmaf(a, wr[j], acc[j]);
        }
    }
    int n0 = (tile < 128 ? tile : tile - 128) * 64;
    float* orow = outp + (size_t)(n0 + lane) * ldo + cb;
    *(float4*)orow       = make_float4(acc[0], acc[1], acc[2], acc[3]);
    *(float4*)(orow + 4) = make_float4(acc[4], acc[5], acc[6], acc[7]);

    // cself on block 255
    if (bid == 255 && t < 64) {
        float a = b1e[t];
        for (int d = 0; d < DIM; d++)
            a += semb[d] * W1e[(size_t)(2 * DIM + d) * 64 + t];
        cself[t] = a;
    }
    // mark out-neighbors of nodeid; first-touch slot assignment
    // slotmap: 0 = none, >0 = slot+1, -1 = claimed/overflow
    int idx64 = detect64(rowp);
    int e = bid * NTD + t;
    if (e < E) {
        int r = edge_idx(rowp, e, idx64);
        if (r == nodeid) {
            int c = edge_idx(colp, e, idx64);
            if (c != nodeid) {
                atomicAdd(&cnt0[c], adjd[e]);
                if (atomicCAS((unsigned int*)&slotmap[c], 0u, 0xFFFFFFFFu) == 0u) {
                    int s = atomicAdd(&flags[1], 1);
                    if (s < SMAX) {
                        nbr[s] = c;
                        __hip_atomic_store(&slotmap[c], s + 1, __ATOMIC_RELAXED,
                                           __HIP_MEMORY_SCOPE_AGENT);
                    }
                }
            }
        }
    }
}

// --- K2: fused classify + gate MLP over all E edges ---
__global__ __launch_bounds__(1024) void k_gates(
        const float* adjd, const float* noise, const float* tmp,
        const float* W2e, const float* b2e,
        const void* rowp, const void* colp, const int* nodep,
        const float* U, const float* V, const float* cself,
        const int* slotmap,
        unsigned int* hashK, float* hashC, float* hashF, float* hashR,
        float* f0s, float* r0s, int E) {
    int idx64 = detect64(rowp);
    int nodeid = nodep[0];
    int e = blockIdx.x * blockDim.x + threadIdx.x;
    if (e >= E) return;
    int r = edge_idx(rowp, e, idx64);
    int c = edge_idx(colp, e, idx64);
    if (r == c) return;
    int spr = slotmap[r];
    int spc = slotmap[c];
    bool fr = spr > 0, fc = spc > 0;
    if (!fr && !fc) return;
    float la = b2e[0];
    const float4* u4 = (const float4*)(U + (size_t)r * 64);
    const float4* v4 = (const float4*)(V + (size_t)c * 64);
    const float4* c4 = (const float4*)cself;
    const float4* w4 = (const float4*)W2e;
#pragma unroll
    for (int d = 0; d < 16; d++) {
        float4 uu = u4[d], vv = v4[d], cc = c4[d], ww = w4[d];
        float h0 = uu.x + vv.x + cc.x;
        float h1 = uu.y + vv.y + cc.y;
        float h2 = uu.z + vv.z + cc.z;
        float h3 = uu.w + vv.w + cc.w;
        la += (h0 > 0.f ? h0 : 0.f) * ww.x + (h1 > 0.f ? h1 : 0.f) * ww.y
            + (h2 > 0.f ? h2 : 0.f) * ww.z + (h3 > 0.f ? h3 : 0.f) * ww.w;
    }
    float nz = noise[e];
    float gi = (logf(nz) - log1pf(-nz) + la) / tmp[0];
    float v = 1.f / (1.f + expf(-gi));
    if (fr) {
        int sr = spr - 1;
        unsigned int key1 = ((unsigned int)(sr << 13) | (unsigned int)c) + 1u;
        int idx = hash_insert(hashK, key1);
        atomicAdd(&hashC[idx], adjd[e]);
        atomicAdd(&hashF[idx], v);
        if (c == nodeid) atomicAdd(&r0s[sr], v);
    }
    if (fc) {
        int sc = spc - 1;
        unsigned int key1 = ((unsigned int)(sc << 13) | (unsigned int)r) + 1u;
        int idx = hash_insert(hashK, key1);
        atomicAdd(&hashR[idx], v);
        if (r == nodeid) atomicAdd(&f0s[sc], v);
    }
}

// --- K3: hash-aggregate into h1acc ---
__global__ __launch_bounds__(1024) void k_hagg(
        const unsigned int* hashK, const float* hashC, const float* hashF,
        const float* hashR, const float* xw, float* h1acc) {
    int gid = blockIdx.x * blockDim.x + threadIdx.x;
    int group = gid >> 7;
    int tg = gid & 127;
    int ngroups = (256 * 1024) >> 7;
    for (int entry = group; entry < HSIZE; entry += ngroups) {
        unsigned int key1 = hashK[entry];
        if (key1 == 0u) continue;
        float wgt = hashC[entry] * (hashF[entry] + hashR[entry]) * 0.5f;
        if (wgt == 0.f) continue;
        unsigned int key = key1 - 1u;
        int s = (int)(key >> 13);
        int k = (int)(key & 8191u);
        atomicAdd(&h1acc[(size_t)s * DIM + tg], wgt * xw[(size_t)k * DIM + tg]);
    }
}

// --- K4: final reduce + softmax ---
__global__ __launch_bounds__(1024) void k_final(
        const int* flags, const float* h1acc, const float* cnt0, const int* nbr,
        const float* f0s, const float* r0s, const float* Wg1, float* out) {
    int t = threadIdx.x;
    __shared__ float sacc[7];
    if (t < 7) sacc[t] = 0.f;
    __syncthreads();
    int ns = flags[1]; if (ns > SMAX) ns = SMAX;
    int wave = t >> 6, lane = t & 63;
    for (int s = wave; s < ns; s += 16) {
        float a0 = cnt0[nbr[s]] * (f0s[s] + r0s[s]) * 0.5f;
        float v0 = h1acc[(size_t)s * DIM + lane];
        float v1 = h1acc[(size_t)s * DIM + lane + 64];
        v0 = v0 > 0.f ? v0 : 0.f;
        v1 = v1 > 0.f ? v1 : 0.f;
        float part[7];
        for (int c = 0; c < 7; c++) {
            float p = v0 * Wg1[lane * 7 + c] + v1 * Wg1[(lane + 64) * 7 + c];
            for (int o = 32; o >= 1; o >>= 1) p += __shfl_xor(p, o, 64);
            part[c] = p;
        }
        if (lane == 0)
            for (int c = 0; c < 7; c++) atomicAdd(&sacc[c], a0 * part[c]);
    }
    __syncthreads();
    if (t == 0) {
        float v[7], m = -1e30f, ssum = 0.f;
        for (int c = 0; c < 7; c++) { v[c] = sacc[c]; if (v[c] > m) m = v[c]; }
        for (int c = 0; c < 7; c++) { v[c] = expf(v[c] - m); ssum += v[c]; }
        for (int c = 0; c < 7; c++) out[c] = v[c] / ssum;
    }
}

extern "C" void kernel_launch(void* const* d_in, const int* in_sizes, int n_in,
                              void* d_out, int out_size, void* d_ws, size_t ws_size,
                              hipStream_t stream) {
    const float* x     = (const float*)d_in[0];
    const float* embed = (const float*)d_in[1];
    const float* adjd  = (const float*)d_in[2];
    const float* noise = (const float*)d_in[3];
    const float* tmp   = (const float*)d_in[4];
    const float* W1e   = (const float*)d_in[5];
    const float* b1e   = (const float*)d_in[6];
    const float* W2e   = (const float*)d_in[7];
    const float* b2e   = (const float*)d_in[8];
    const float* Wg0   = (const float*)d_in[9];
    const float* Wg1   = (const float*)d_in[10];
    const void*  rowp  = d_in[11];
    const void*  colp  = d_in[12];
    const int*   nodep = (const int*)d_in[13];
    int E = in_sizes[3];   // noise is float32[E]

    char* w = (char*)d_ws;
    size_t off = 0;
    auto alloc = [&](size_t bytes) -> char* {
        char* p = w + off;
        off = (off + bytes + 255) & ~(size_t)255;
        return p;
    };
    float*        cself   = (float*)alloc(64 * 4);
    int*          nbr     = (int*)  alloc(SMAX * 4);
    float*        U       = (float*)alloc((size_t)NNODES * 64 * 4);
    float*        V       = (float*)alloc((size_t)NNODES * 64 * 4);
    float*        xw      = (float*)alloc((size_t)NNODES * DIM * 4);
    char*         zstart  = w + off;
    int*          flags   = (int*)  alloc(256);
    int*          slotmap = (int*)  alloc((size_t)NNODES * 4);
    float*        cnt0    = (float*)alloc((size_t)NNODES * 4);
    float*        f0s     = (float*)alloc(SMAX * 4);
    float*        r0s     = (float*)alloc(SMAX * 4);
    unsigned int* hashK   = (unsigned int*)alloc((size_t)HSIZE * 4);
    float*        hashC   = (float*)alloc((size_t)HSIZE * 4);
    float*        hashF   = (float*)alloc((size_t)HSIZE * 4);
    float*        hashR   = (float*)alloc((size_t)HSIZE * 4);
    float*        h1acc   = (float*)alloc((size_t)SMAX * DIM * 4);
    size_t zbytes  = (size_t)((w + off) - zstart);
    int n4 = (int)(zbytes / 16);

    k_zero<<<(n4 + 255) / 256, 256, 0, stream>>>((float4*)zstart, n4);
    k_dense<<<NBD, NTD, 0, stream>>>(embed, x, W1e, b1e, Wg0, nodep, rowp, colp,
                                     adjd, U, V, xw, cself, flags, cnt0, nbr,
                                     slotmap, E);
    k_gates<<<E / 1024, 1024, 0, stream>>>(adjd, noise, tmp, W2e, b2e,
                                           rowp, colp, nodep, U, V, cself,
                                           slotmap, hashK, hashC, hashF, hashR,
                                           f0s, r0s, E);
    k_hagg<<<256, 1024, 0, stream>>>(hashK, hashC, hashF, hashR, xw, h1acc);
    k_final<<<1, 1024, 0, stream>>>(flags, h1acc, cnt0, nbr, f0s, r0s, Wg1,
                                    (float*)d_out);
}

// Round 11
// 53.376 us; speedup vs baseline: 1.2745x; 1.2745x over previous
//
#include <hip/hip_runtime.h>
#include <hip/hip_bf16.h>
#include <math.h>

#define NNODES 8192
#define DIM 128
#define SMAX 128
#define HSIZE 16384   // hash table capacity (power of 2)
#define NBD 256
#define NTD 1024
#define LDA 132       // padded LDS stride: 16B-aligned, uniform b128 bank spread

// Per-thread index-dtype detection: reads first 4 int64-interpretations of row.
__device__ __forceinline__ int detect64(const void* rowp) {
    const long long* p = (const long long*)rowp;
    int is64 = 1;
#pragma unroll
    for (int i = 0; i < 4; i++) {
        long long v = p[i];
        if (v < 0 || v >= NNODES) is64 = 0;
    }
    return is64;
}

__device__ __forceinline__ int edge_idx(const void* p, int e, int idx64) {
    if (idx64) return (int)((const long long*)p)[e];
    return ((const int*)p)[e];
}

__device__ __forceinline__ int hash_insert(unsigned int* hashK, unsigned int key1) {
    unsigned int h = (key1 * 2654435761u) & (HSIZE - 1);
    for (;;) {
        unsigned int prev = atomicCAS(&hashK[h], 0u, key1);
        if (prev == 0u || prev == key1) return (int)h;
        h = (h + 1) & (HSIZE - 1);
    }
}

// --- K0: zero scratch (rocclr fillBuffer is ~39us even for small sizes) ---
__global__ __launch_bounds__(256) void k_zero(float4* z, int n4) {
    int i = blockIdx.x * blockDim.x + threadIdx.x;
    if (i < n4) z[i] = make_float4(0.f, 0.f, 0.f, 0.f);
}

// --- K1: dense precompute (U,V,xw,cself) + nodeid mark & slot assignment ---
// lane = output row: A via per-lane ds_read_b128; W batch loaded coalesced
// into lanes, broadcast via v_readlane (VALU pipe).
// LESSONS: r8 per-element broadcast ds_reads = LDS-pipe bound (~40us).
//          r10 W via readfirstlane s_loads = SMEM-pipe bound + lgkmcnt(0)
//          serialization (measured 41us, VALUBusy 11%). readlane form = ~11us.
__global__ __launch_bounds__(NTD) void k_dense(
        const float* embed, const float* x, const float* W1e, const float* b1e,
        const float* Wg0, const int* nodep, const void* rowp, const void* colp,
        const float* adjd,
        float* U, float* V, float* xw, float* cself,
        int* flags, float* cnt0, int* nbr, int* slotmap, int E) {
    int bid = blockIdx.x;
    int t = threadIdx.x;
    int w = t >> 6;
    int lane = t & 63;
    int nodeid = nodep[0];
    __shared__ float smf[64 * LDA];   // 33.8 KB
    __shared__ float semb[DIM];

    int tile = bid;
    const float* src = (tile < 128) ? embed + (size_t)tile * 64 * DIM
                                    : x + (size_t)(tile - 128) * 64 * DIM;
    for (int i = t; i < 64 * DIM; i += NTD)
        smf[(i >> 7) * LDA + (i & 127)] = src[i];
    if (bid == 255 && t < DIM) semb[t] = embed[(size_t)nodeid * DIM + t];
    __syncthreads();

    const float* Wsrc;
    float* outp;
    int ldw, ldo, cb, doff;
    if (tile < 128) {
        Wsrc = W1e; ldw = 64; ldo = 64;
        if (w < 8) { doff = 0;   cb = w * 8;       outp = U; }
        else       { doff = 128; cb = (w - 8) * 8; outp = V; }
    } else {
        Wsrc = Wg0; ldw = DIM; ldo = DIM; doff = 0; cb = w * 8; outp = xw;
    }

    int row = lane;
    float acc[8] = {0, 0, 0, 0, 0, 0, 0, 0};
    for (int d0 = 0; d0 < DIM; d0 += 8) {
        // lane l holds W[doff+d0+(l>>3)][cb+(l&7)] -- 8 d-rows x 8 cols batch
        float wb = Wsrc[(size_t)(doff + d0 + (lane >> 3)) * ldw + cb + (lane & 7)];
        float4 a0 = *(const float4*)&smf[row * LDA + d0];
        float4 a1 = *(const float4*)&smf[row * LDA + d0 + 4];
#pragma unroll
        for (int k = 0; k < 8; k++) {
            float a = (k < 4) ? (&a0.x)[k] : (&a1.x)[k - 4];
#pragma unroll
            for (int j = 0; j < 8; j++) {
                float wv = __uint_as_float(
                    __builtin_amdgcn_readlane(__float_as_uint(wb), k * 8 + j));
                acc[j] = fmaf(a, wv, acc[j]);
            }
        }
    }
    int n0 = (tile < 128 ? tile : tile - 128) * 64;
    float* orow = outp + (size_t)(n0 + row) * ldo + cb;
    *(float4*)orow       = make_float4(acc[0], acc[1], acc[2], acc[3]);
    *(float4*)(orow + 4) = make_float4(acc[4], acc[5], acc[6], acc[7]);

    // cself on block 255
    if (bid == 255 && t < 64) {
        float a = b1e[t];
        for (int d = 0; d < DIM; d++)
            a += semb[d] * W1e[(size_t)(2 * DIM + d) * 64 + t];
        cself[t] = a;
    }
    // mark out-neighbors of nodeid; first-touch slot assignment
    // slotmap: 0 = none, >0 = slot+1, -1 = claimed/overflow
    int idx64 = detect64(rowp);
    int e = bid * NTD + t;
    if (e < E) {
        int r = edge_idx(rowp, e, idx64);
        if (r == nodeid) {
            int c = edge_idx(colp, e, idx64);
            if (c != nodeid) {
                atomicAdd(&cnt0[c], adjd[e]);
                if (atomicCAS((unsigned int*)&slotmap[c], 0u, 0xFFFFFFFFu) == 0u) {
                    int s = atomicAdd(&flags[1], 1);
                    if (s < SMAX) {
                        nbr[s] = c;
                        __hip_atomic_store(&slotmap[c], s + 1, __ATOMIC_RELAXED,
                                           __HIP_MEMORY_SCOPE_AGENT);
                    }
                }
            }
        }
    }
}

// --- K2: fused classify + gate MLP over all E edges ---
__global__ __launch_bounds__(1024) void k_gates(
        const float* adjd, const float* noise, const float* tmp,
        const float* W2e, const float* b2e,
        const void* rowp, const void* colp, const int* nodep,
        const float* U, const float* V, const float* cself,
        const int* slotmap,
        unsigned int* hashK, float* hashC, float* hashF, float* hashR,
        float* f0s, float* r0s, int E) {
    int idx64 = detect64(rowp);
    int nodeid = nodep[0];
    int e = blockIdx.x * blockDim.x + threadIdx.x;
    if (e >= E) return;
    int r = edge_idx(rowp, e, idx64);
    int c = edge_idx(colp, e, idx64);
    if (r == c) return;
    int spr = slotmap[r];
    int spc = slotmap[c];
    bool fr = spr > 0, fc = spc > 0;
    if (!fr && !fc) return;
    float la = b2e[0];
    const float4* u4 = (const float4*)(U + (size_t)r * 64);
    const float4* v4 = (const float4*)(V + (size_t)c * 64);
    const float4* c4 = (const float4*)cself;
    const float4* w4 = (const float4*)W2e;
#pragma unroll
    for (int d = 0; d < 16; d++) {
        float4 uu = u4[d], vv = v4[d], cc = c4[d], ww = w4[d];
        float h0 = uu.x + vv.x + cc.x;
        float h1 = uu.y + vv.y + cc.y;
        float h2 = uu.z + vv.z + cc.z;
        float h3 = uu.w + vv.w + cc.w;
        la += (h0 > 0.f ? h0 : 0.f) * ww.x + (h1 > 0.f ? h1 : 0.f) * ww.y
            + (h2 > 0.f ? h2 : 0.f) * ww.z + (h3 > 0.f ? h3 : 0.f) * ww.w;
    }
    float nz = noise[e];
    float gi = (logf(nz) - log1pf(-nz) + la) / tmp[0];
    float v = 1.f / (1.f + expf(-gi));
    if (fr) {
        int sr = spr - 1;
        unsigned int key1 = ((unsigned int)(sr << 13) | (unsigned int)c) + 1u;
        int idx = hash_insert(hashK, key1);
        atomicAdd(&hashC[idx], adjd[e]);
        atomicAdd(&hashF[idx], v);
        if (c == nodeid) atomicAdd(&r0s[sr], v);
    }
    if (fc) {
        int sc = spc - 1;
        unsigned int key1 = ((unsigned int)(sc << 13) | (unsigned int)r) + 1u;
        int idx = hash_insert(hashK, key1);
        atomicAdd(&hashR[idx], v);
        if (r == nodeid) atomicAdd(&f0s[sc], v);
    }
}

// --- K3: hash-aggregate into h1acc ---
__global__ __launch_bounds__(1024) void k_hagg(
        const unsigned int* hashK, const float* hashC, const float* hashF,
        const float* hashR, const float* xw, float* h1acc) {
    int gid = blockIdx.x * blockDim.x + threadIdx.x;
    int group = gid >> 7;
    int tg = gid & 127;
    int ngroups = (256 * 1024) >> 7;
    for (int entry = group; entry < HSIZE; entry += ngroups) {
        unsigned int key1 = hashK[entry];
        if (key1 == 0u) continue;
        float wgt = hashC[entry] * (hashF[entry] + hashR[entry]) * 0.5f;
        if (wgt == 0.f) continue;
        unsigned int key = key1 - 1u;
        int s = (int)(key >> 13);
        int k = (int)(key & 8191u);
        atomicAdd(&h1acc[(size_t)s * DIM + tg], wgt * xw[(size_t)k * DIM + tg]);
    }
}

// --- K4: final reduce + softmax ---
__global__ __launch_bounds__(1024) void k_final(
        const int* flags, const float* h1acc, const float* cnt0, const int* nbr,
        const float* f0s, const float* r0s, const float* Wg1, float* out) {
    int t = threadIdx.x;
    __shared__ float sacc[7];
    if (t < 7) sacc[t] = 0.f;
    __syncthreads();
    int ns = flags[1]; if (ns > SMAX) ns = SMAX;
    int wave = t >> 6, lane = t & 63;
    for (int s = wave; s < ns; s += 16) {
        float a0 = cnt0[nbr[s]] * (f0s[s] + r0s[s]) * 0.5f;
        float v0 = h1acc[(size_t)s * DIM + lane];
        float v1 = h1acc[(size_t)s * DIM + lane + 64];
        v0 = v0 > 0.f ? v0 : 0.f;
        v1 = v1 > 0.f ? v1 : 0.f;
        float part[7];
        for (int c = 0; c < 7; c++) {
            float p = v0 * Wg1[lane * 7 + c] + v1 * Wg1[(lane + 64) * 7 + c];
            for (int o = 32; o >= 1; o >>= 1) p += __shfl_xor(p, o, 64);
            part[c] = p;
        }
        if (lane == 0)
            for (int c = 0; c < 7; c++) atomicAdd(&sacc[c], a0 * part[c]);
    }
    __syncthreads();
    if (t == 0) {
        float v[7], m = -1e30f, ssum = 0.f;
        for (int c = 0; c < 7; c++) { v[c] = sacc[c]; if (v[c] > m) m = v[c]; }
        for (int c = 0; c < 7; c++) { v[c] = expf(v[c] - m); ssum += v[c]; }
        for (int c = 0; c < 7; c++) out[c] = v[c] / ssum;
    }
}

extern "C" void kernel_launch(void* const* d_in, const int* in_sizes, int n_in,
                              void* d_out, int out_size, void* d_ws, size_t ws_size,
                              hipStream_t stream) {
    const float* x     = (const float*)d_in[0];
    const float* embed = (const float*)d_in[1];
    const float* adjd  = (const float*)d_in[2];
    const float* noise = (const float*)d_in[3];
    const float* tmp   = (const float*)d_in[4];
    const float* W1e   = (const float*)d_in[5];
    const float* b1e   = (const float*)d_in[6];
    const float* W2e   = (const float*)d_in[7];
    const float* b2e   = (const float*)d_in[8];
    const float* Wg0   = (const float*)d_in[9];
    const float* Wg1   = (const float*)d_in[10];
    const void*  rowp  = d_in[11];
    const void*  colp  = d_in[12];
    const int*   nodep = (const int*)d_in[13];
    int E = in_sizes[3];   // noise is float32[E]

    char* w = (char*)d_ws;
    size_t off = 0;
    auto alloc = [&](size_t bytes) -> char* {
        char* p = w + off;
        off = (off + bytes + 255) & ~(size_t)255;
        return p;
    };
    float*        cself   = (float*)alloc(64 * 4);
    int*          nbr     = (int*)  alloc(SMAX * 4);
    float*        U       = (float*)alloc((size_t)NNODES * 64 * 4);
    float*        V       = (float*)alloc((size_t)NNODES * 64 * 4);
    float*        xw      = (float*)alloc((size_t)NNODES * DIM * 4);
    char*         zstart  = w + off;
    int*          flags   = (int*)  alloc(256);
    int*          slotmap = (int*)  alloc((size_t)NNODES * 4);
    float*        cnt0    = (float*)alloc((size_t)NNODES * 4);
    float*        f0s     = (float*)alloc(SMAX * 4);
    float*        r0s     = (float*)alloc(SMAX * 4);
    unsigned int* hashK   = (unsigned int*)alloc((size_t)HSIZE * 4);
    float*        hashC   = (float*)alloc((size_t)HSIZE * 4);
    float*        hashF   = (float*)alloc((size_t)HSIZE * 4);
    float*        hashR   = (float*)alloc((size_t)HSIZE * 4);
    float*        h1acc   = (float*)alloc((size_t)SMAX * DIM * 4);
    size_t zbytes  = (size_t)((w + off) - zstart);
    int n4 = (int)(zbytes / 16);

    k_zero<<<(n4 + 255) / 256, 256, 0, stream>>>((float4*)zstart, n4);
    k_dense<<<NBD, NTD, 0, stream>>>(embed, x, W1e, b1e, Wg0, nodep, rowp, colp,
                                     adjd, U, V, xw, cself, flags, cnt0, nbr,
                                     slotmap, E);
    k_gates<<<E / 1024, 1024, 0, stream>>>(adjd, noise, tmp, W2e, b2e,
                                           rowp, colp, nodep, U, V, cself,
                                           slotmap, hashK, hashC, hashF, hashR,
                                           f0s, r0s, E);
    k_hagg<<<256, 1024, 0, stream>>>(hashK, hashC, hashF, hashR, xw, h1acc);
    k_final<<<1, 1024, 0, stream>>>(flags, h1acc, cnt0, nbr, f0s, r0s, Wg1,
                                    (float*)d_out);
}